// Round 16
// baseline (349.975 us; speedup 1.0000x reference)
//
#include <hip/hip_runtime.h>

typedef float f32x4 __attribute__((ext_vector_type(4)));
typedef short bf16x8 __attribute__((ext_vector_type(8)));
typedef unsigned short u16;
typedef unsigned int u32;

#define SCALE 0.0625f
#define MFMA32(a, b, c) __builtin_amdgcn_mfma_f32_16x16x32_bf16((a), (b), (c), 0, 0, 0)

__device__ inline u16 f2bf(float x) {
  u32 u = __float_as_uint(x);
  u32 r = u + 0x7FFFu + ((u >> 16) & 1u);
  return (u16)(r >> 16);
}
__device__ inline float bf2f(u16 h) { return __uint_as_float(((u32)h) << 16); }
// packed f32x2 -> bf16x2 (RNE), single VALU op
__device__ __forceinline__ u32 cvtpk(float a, float b) {
  u32 r;
  asm("v_cvt_pk_bf16_f32 %0, %1, %2" : "=v"(r) : "v"(a), "v"(b));
  return r;
}

// async global->LDS, 16B per lane; LDS dest is wave-uniform base + lane*16
__device__ __forceinline__ void gld16(const void* g, void* l) {
  __builtin_amdgcn_global_load_lds(
      (const __attribute__((address_space(1))) unsigned int*)(uintptr_t)g,
      (__attribute__((address_space(3))) unsigned int*)(uintptr_t)l, 16, 0, 0);
}

// ---------------------------------------------------------------------------
// Transpose+split W matrices: W[k][n] fp32 -> Wt_hi/lo[n][k] bf16.
// ---------------------------------------------------------------------------
__global__ __launch_bounds__(256) void convert_w(
    const float* __restrict__ Wq, const float* __restrict__ Wk, const float* __restrict__ Wv,
    u16* __restrict__ qh, u16* __restrict__ qlo2, u16* __restrict__ kh, u16* __restrict__ klo2,
    u16* __restrict__ vh, u16* __restrict__ vlo2) {
  int idx = blockIdx.x * 256 + threadIdx.x;
  const float* src;
  u16 *dh, *dl;
  int KD;
  const int nq = 416 * 256;
  if (idx < nq) {
    src = Wq; dh = qh; dl = qlo2; KD = 416;
  } else if (idx < 2 * nq) {
    idx -= nq; src = Wk; dh = kh; dl = klo2; KD = 416;
  } else {
    idx -= 2 * nq;
    if (idx >= 384 * 256) return;
    src = Wv; dh = vh; dl = vlo2; KD = 384;
  }
  int k = idx >> 8, n = idx & 255;
  float x = src[idx];
  u16 h = f2bf(x);
  dh[n * KD + k] = h;
  dl[n * KD + k] = f2bf(x - bf2f(h));
}

// ---------------------------------------------------------------------------
// Projection GEMM, 2-term split-bf16 MFMA: C = ah*(Wh+Wl).   (r13-proven)
// OUT=0: flat hi [m][256] (Q).
// OUT=1: K (hi) into kvswz per-(km,kt64) 32768-u16 block:
//        slot = row*256 + (((c + 5*row)&31)<<3) + e   (row=j&63, c=d>>3, e=d&7)
// OUT=2: V (hi) at +16384 u16: slot = 16384 + (d>>5)*2048 +
//        ((((j&63)>>3)*32 + (d&31))<<3) + (j&7)
// ---------------------------------------------------------------------------
template <int KD, int OUT>
__global__ __launch_bounds__(256, 3) void proj_mfma(
    const float* __restrict__ A, const u16* __restrict__ wth, const u16* __restrict__ wtl,
    u16* __restrict__ oh) {
  __shared__ u16 Ah[64 * 32];
  __shared__ u16 Wh[256 * 32], Wl[256 * 32];
  const int t = threadIdx.x;
  const int w = t >> 6, l = t & 63;
  const int lr = l & 15, lk = l >> 4;
  const int m0 = blockIdx.x * 64;
  f32x4 acc[16];
#pragma unroll
  for (int i = 0; i < 16; ++i) acc[i] = {};
  const int arow = t >> 2, ac = t & 3;
  const int acp = (ac + (arow >> 1)) & 3;
  for (int k0 = 0; k0 < KD; k0 += 32) {
    __syncthreads();
    {
      const float* s1 = A + (size_t)(m0 + arow) * KD + k0 + ac * 8;
      float4 f1 = *(const float4*)s1;
      float4 f2 = *(const float4*)(s1 + 4);
      u32 hv[4];
      hv[0] = cvtpk(f1.x, f1.y);
      hv[1] = cvtpk(f1.z, f1.w);
      hv[2] = cvtpk(f2.x, f2.y);
      hv[3] = cvtpk(f2.z, f2.w);
      *(bf16x8*)(Ah + arow * 32 + acp * 8) = *(bf16x8*)hv;
#pragma unroll
      for (int i = 0; i < 4; ++i) {
        int ch = t + i * 256;
        int n = ch >> 2, c = ch & 3;
        int cp = (c + (n >> 1)) & 3;
        *(bf16x8*)(Wh + n * 32 + cp * 8) = *(const bf16x8*)(wth + (size_t)n * KD + k0 + c * 8);
        *(bf16x8*)(Wl + n * 32 + cp * 8) = *(const bf16x8*)(wtl + (size_t)n * KD + k0 + c * 8);
      }
    }
    __syncthreads();
    const int row = w * 16 + lr;
    const int rcp = (lk + (row >> 1)) & 3;
    bf16x8 ah = *(const bf16x8*)(Ah + row * 32 + rcp * 8);
#pragma unroll
    for (int fc = 0; fc < 16; ++fc) {
      int n = lr + 16 * fc;
      int cp = (lk + (n >> 1)) & 3;
      bf16x8 bh = *(const bf16x8*)(Wh + n * 32 + cp * 8);
      bf16x8 bl = *(const bf16x8*)(Wl + n * 32 + cp * 8);
      acc[fc] = MFMA32(ah, bh, acc[fc]);
      acc[fc] = MFMA32(ah, bl, acc[fc]);
    }
  }
  if (OUT == 0) {
#pragma unroll
    for (int fc = 0; fc < 16; ++fc) {
      int n = lr + 16 * fc;
#pragma unroll
      for (int r = 0; r < 4; ++r) {
        int m = m0 + w * 16 + lk * 4 + r;
        oh[(size_t)m * 256 + n] = f2bf(acc[fc][r]);
      }
    }
  } else if (OUT == 1) {
#pragma unroll
    for (int r = 0; r < 4; ++r) {
      int m = m0 + w * 16 + lk * 4 + r;
      int km = m / 576;
      int j = m - km * 576;
      int kt = j >> 6, row = j & 63;
      size_t rowbase = (size_t)(km * 9 + kt) * 32768 + (row << 8);
#pragma unroll
      for (int fc = 0; fc < 16; ++fc) {
        int c = (lr >> 3) + 2 * fc;
        size_t slot = rowbase + (size_t)((((c + 5 * row) & 31) << 3) + (lr & 7));
        oh[slot] = f2bf(acc[fc][r]);
      }
    }
  } else {
    const int km = m0 / 576;
    const int j0 = (m0 % 576) + w * 16 + lk * 4;
    const int kt = j0 >> 6;
    const int jl = j0 & 63;
    const int kc = jl >> 3, e0 = jl & 7;
    const size_t vbase = (size_t)(km * 9 + kt) * 32768 + 16384;
#pragma unroll
    for (int fc = 0; fc < 16; ++fc) {
      size_t slot = vbase + (size_t)((fc >> 1) * 2048 + ((kc * 32 + lr + (fc & 1) * 16) << 3) + e0);
      u32 pk[2];
      pk[0] = cvtpk(acc[fc][0], acc[fc][1]);
      pk[1] = cvtpk(acc[fc][2], acc[fc][3]);
      *(uint2*)(oh + slot) = *(uint2*)pk;
    }
  }
}

// ---------------------------------------------------------------------------
// Flash attention: 512 thr / 8 waves = (wq 0..3) x (wk 0..1); 64 q x 64
// keys/kt (9 iterations).  S = qh*kh; PV = ph*vh.  K staged to LDS (32 KB);
// V goes straight from kvswz into registers (per-wave disjoint slice, layout
// == B-fragment order), double-buffered across iterations so HBM/L2 latency
// hides under a full QK+softmax phase.  LDS ~44 KB -> 3 blocks/CU.
// launch_bounds (512,4): VGPR cap 128, no spill (r12's failure was the
// (512,6)=85-reg cap).  2 barriers/kt, counted vmcnt only (steady state
// alternates {4 V-loads, 4 K-DMAs}).  m==0 softmax.  R written bf16.
// ---------------------------------------------------------------------------
__global__ __launch_bounds__(512, 4) void attn_kernel(
    const u16* __restrict__ qhi, const u16* __restrict__ kvswz,
    u16* __restrict__ rpartT, float* __restrict__ invl) {
  __shared__ u16 KV[16384];  // Kh only: 64 rows x 256 u16 = 32 KB
  __shared__ u16 Ph[64 * 72];
  __shared__ float lred[2][64], mred[2][64];
  __shared__ float invs[64];
  const int t = threadIdx.x;
  const int w = t >> 6, l = t & 63;
  const int lr = l & 15, lk = l >> 4;
  const int wq = w >> 1, wk = w & 1;
  // XCD-cluster swizzle: all 36 blocks of one km land on xcd = km%8.
  const int L = blockIdx.x;
  const int xcd = L & 7, slot = L >> 3;
  const int km = xcd + 8 * (slot / 36);
  const int inner = slot % 36;
  const int b = inner & 3, qb = inner >> 2;
  const int qw = qb * 64 + wq * 16;

  // Q fragments (B-operand of swapped QK: col=q=lr, k-chunk lk*8 + s*32)
  bf16x8 qh[8];
  {
    const size_t qoff = ((size_t)(b * 576 + qw + lr)) * 256 + lk * 8;
#pragma unroll
    for (int s = 0; s < 8; ++s) qh[s] = *(const bf16x8*)(qhi + qoff + s * 32);
  }

  f32x4 o[4][2];
#pragma unroll
  for (int i = 0; i < 4; ++i)
#pragma unroll
    for (int j = 0; j < 2; ++j) o[i][j] = {};
  float m_part = -1e30f, l_part = 0.f;  // per-lane: q=wq*16+lr, keys of wk half

  const char* kvb = (const char*)kvswz + (size_t)(km * 9) * 65536;
  char* lds0 = (char*)&KV[0];

  auto STAGE_K = [&](int kt) {
    // full K tile: 32768 B = 4 regions x (512 thr x 16 B)
    const char* src = kvb + (size_t)kt * 65536 + t * 16;
    char* dst = lds0 + t * 16;
#pragma unroll
    for (int i = 0; i < 4; ++i) gld16(src + i * 8192, dst + i * 8192);
  };

  // per-lane V slice base (B-fragment order in kvswz)
  const char* vlane = kvb + 32768 + w * 4096 + (lk * 32 + lr) * 16;

  // prologue: V(0) regs + K(0) LDS, drain everything once, barrier.
  asm volatile("s_waitcnt vmcnt(0)" ::: "memory");  // Q drained: clean FIFO
  __builtin_amdgcn_sched_barrier(0);
  bf16x8 v00 = *(const bf16x8*)(vlane);
  bf16x8 v01 = *(const bf16x8*)(vlane + 256);
  bf16x8 v10 = *(const bf16x8*)(vlane + 2048);
  bf16x8 v11 = *(const bf16x8*)(vlane + 2304);
  __builtin_amdgcn_sched_barrier(0);
  STAGE_K(0);
  asm volatile("s_waitcnt vmcnt(0)" ::: "memory");  // V(0) regs + K(0) landed
  __builtin_amdgcn_sched_barrier(0);
  __builtin_amdgcn_s_barrier();
  __builtin_amdgcn_sched_barrier(0);

  const int krow0 = wk * 32 + lr;
  const int krow1 = wk * 32 + 16 + lr;

  for (int kt = 0; kt < 9; ++kt) {
    // ---- QK^T: A = K-frags (two 16-key blocks of wk half), B = Q
    f32x4 s0 = {}, s1 = {};
    __builtin_amdgcn_s_setprio(1);
#pragma unroll
    for (int s = 0; s < 8; ++s) {
      const int cc0 = ((s * 4 + lk) + 5 * krow0) & 31;
      const int cc1 = ((s * 4 + lk) + 5 * krow1) & 31;
      bf16x8 k0 = *(const bf16x8*)(KV + krow0 * 256 + cc0 * 8);
      bf16x8 k1 = *(const bf16x8*)(KV + krow1 * 256 + cc1 * 8);
      s0 = MFMA32(k0, qh[s], s0);
      s1 = MFMA32(k1, qh[s], s1);
    }
    __builtin_amdgcn_s_setprio(0);

    // ---- P = exp(S*scale): lane q = wq*16+lr; keys wk*32 + {lk*4.., 16+lk*4..}
    float e0[4], e1[4];
#pragma unroll
    for (int r = 0; r < 4; ++r) {
      float a0 = s0[r] * SCALE;
      float a1 = s1[r] * SCALE;
      m_part = fmaxf(m_part, fmaxf(a0, a1));
      e0[r] = __expf(a0);
      e1[r] = __expf(a1);
      l_part += e0[r] + e1[r];
    }
    {
      u32 pk0[2], pk1[2];
      pk0[0] = cvtpk(e0[0], e0[1]);
      pk0[1] = cvtpk(e0[2], e0[3]);
      pk1[0] = cvtpk(e1[0], e1[1]);
      pk1[1] = cvtpk(e1[2], e1[3]);
      int pb = (wq * 16 + lr) * 72 + wk * 32 + lk * 4;
      *(uint2*)(Ph + pb) = *(uint2*)pk0;
      *(uint2*)(Ph + pb + 16) = *(uint2*)pk1;
    }
    asm volatile("s_waitcnt lgkmcnt(0)" ::: "memory");  // K reads + P writes done
    __builtin_amdgcn_sched_barrier(0);
    __builtin_amdgcn_s_barrier();  // B1: P visible, K region free
    __builtin_amdgcn_sched_barrier(0);

    const int ktn = kt < 8 ? kt + 1 : 8;
    STAGE_K(ktn);  // 4 DMAs, fly under PV
    __builtin_amdgcn_sched_barrier(0);
    asm volatile("s_waitcnt vmcnt(4)" ::: "memory");  // V(kt) regs landed (K DMAs remain)
    __builtin_amdgcn_sched_barrier(0);

    // ---- PV: wave covers d = w*32 + dt*16 + lr, keys in two 32-halves
    __builtin_amdgcn_s_setprio(1);
#pragma unroll
    for (int qt = 0; qt < 4; ++qt) {
      bf16x8 pa0 = *(const bf16x8*)(Ph + (qt * 16 + lr) * 72 + lk * 8);
      bf16x8 pa1 = *(const bf16x8*)(Ph + (qt * 16 + lr) * 72 + 32 + lk * 8);
      o[qt][0] = MFMA32(pa0, v00, o[qt][0]);
      o[qt][1] = MFMA32(pa0, v01, o[qt][1]);
      o[qt][0] = MFMA32(pa1, v10, o[qt][0]);
      o[qt][1] = MFMA32(pa1, v11, o[qt][1]);
    }
    __builtin_amdgcn_s_setprio(0);

    // ---- prefetch V(kt+1) into regs (a full QK phase to land)
    {
      const char* vb = vlane + (size_t)ktn * 65536;
      v00 = *(const bf16x8*)(vb);
      v01 = *(const bf16x8*)(vb + 256);
      v10 = *(const bf16x8*)(vb + 2048);
      v11 = *(const bf16x8*)(vb + 2304);
    }
    __builtin_amdgcn_sched_barrier(0);
    asm volatile("s_waitcnt lgkmcnt(0)" ::: "memory");  // P reads done
    __builtin_amdgcn_sched_barrier(0);
    asm volatile("s_waitcnt vmcnt(4)" ::: "memory");  // K(kt+1) landed (V loads remain)
    __builtin_amdgcn_sched_barrier(0);
    __builtin_amdgcn_s_barrier();  // B2: K ready, P region free
    __builtin_amdgcn_sched_barrier(0);
  }

  // ---- stats: lane q=wq*16+lr; combine lk groups then wk halves
  {
    float lv = l_part, mv = m_part;
    lv += __shfl_xor(lv, 16, 64);
    mv = fmaxf(mv, __shfl_xor(mv, 16, 64));
    lv += __shfl_xor(lv, 32, 64);
    mv = fmaxf(mv, __shfl_xor(mv, 32, 64));
    if (l < 16) {
      lred[wk][wq * 16 + l] = lv;
      mred[wk][wq * 16 + l] = mv;
    }
  }
  __syncthreads();
  if (w == 0) {
    float ls = lred[0][l] + lred[1][l];
    float mv = fmaxf(mred[0][l], mred[1][l]);
    invs[l] = 1.0f / ls;
    invl[(size_t)(b * 80 + km) * 576 + qb * 64 + l] = __expf(mv) / ls;
  }
  __syncthreads();

  u16* dst = rpartT + (size_t)(b * 80 + km) * 147456;
#pragma unroll
  for (int qt = 0; qt < 4; ++qt) {
    float iv[4];
#pragma unroll
    for (int r = 0; r < 4; ++r) iv[r] = invs[qt * 16 + lk * 4 + r];
#pragma unroll
    for (int dt = 0; dt < 2; ++dt) {
      int d = w * 32 + dt * 16 + lr;
      u32 pk[2];
      pk[0] = cvtpk(o[qt][dt][0] * iv[0], o[qt][dt][1] * iv[1]);
      pk[1] = cvtpk(o[qt][dt][2] * iv[2], o[qt][dt][3] * iv[3]);
      *(uint2*)(dst + (size_t)d * 576 + qb * 64 + qt * 16 + lk * 4) = *(uint2*)pk;
    }
  }
}

// ---------------------------------------------------------------------------
// Weights: s[b,k,m] = mean_n 1/l_ref ; w = gate(p) * s / (sum_m s + 1e-8)
// ---------------------------------------------------------------------------
__global__ __launch_bounds__(256) void weight_kernel(const float* __restrict__ invl,
                                                     const float* __restrict__ p,
                                                     float* __restrict__ wout) {
  const int k = blockIdx.x, b = blockIdx.y;
  __shared__ float sm[10];
  __shared__ float red[4];
  const int t = threadIdx.x;
  for (int m = 0; m < 10; ++m) {
    float part = 0.f;
    for (int n = t; n < 576; n += 256)
      part += invl[(size_t)((b * 8 + k) * 10 + m) * 576 + n];
#pragma unroll
    for (int off = 32; off; off >>= 1) part += __shfl_down(part, off, 64);
    if ((t & 63) == 0) red[t >> 6] = part;
    __syncthreads();
    if (t == 0) sm[m] = (red[0] + red[1] + red[2] + red[3]) * (1.0f / 576.0f);
    __syncthreads();
  }
  if (t == 0) {
    float tot = 0.f;
    for (int m = 0; m < 10; ++m) tot += sm[m];
    float pmax = fmaxf(fmaxf(p[0 * 8 + k], p[1 * 8 + k]), fmaxf(p[2 * 8 + k], p[3 * 8 + k]));
    float gate = (pmax >= 0.01f) ? p[b * 8 + k] : 0.0f;
    for (int m = 0; m < 10; ++m)
      wout[(b * 8 + k) * 10 + m] = gate * sm[m] / (tot + 1e-8f);
  }
}

// ---------------------------------------------------------------------------
// out[b][d][n] = sum_km w[b,km] * bf2f(rpartT[b,km][d][n])
// ---------------------------------------------------------------------------
__global__ __launch_bounds__(256) void reduce_out_k(const u16* __restrict__ rpartT,
                                                    const float* __restrict__ wbuf,
                                                    float* __restrict__ out) {
  int idx = blockIdx.x * 256 + threadIdx.x;
  int b = idx / 147456;
  size_t off = (size_t)(idx % 147456);
  const u16* base = rpartT + (size_t)b * 80 * 147456 + off;
  const float* wp = wbuf + b * 80;
  float acc = 0.f;
#pragma unroll 8
  for (int g = 0; g < 80; ++g)
    acc += wp[g] * __uint_as_float(((u32)base[(size_t)g * 147456]) << 16);
  out[idx] = acc;
}

// ---------------------------------------------------------------------------
extern "C" void kernel_launch(void* const* d_in, const int* in_sizes, int n_in,
                              void* d_out, int out_size, void* d_ws, size_t ws_size,
                              hipStream_t stream) {
  const float* Q = (const float*)d_in[0];
  const float* dbk = (const float*)d_in[1];
  const float* dbv = (const float*)d_in[2];
  const float* p = (const float*)d_in[3];
  const float* Wq = (const float*)d_in[4];
  const float* Wk = (const float*)d_in[5];
  const float* Wv = (const float*)d_in[6];
  float* out = (float*)d_out;
  char* ws = (char*)d_ws;

  u16* qhi = (u16*)(ws);                    // 1,179,648 B
  u16* kvswz = (u16*)(ws + 2359296);        // 80*9*65536 = 47,185,920 B
  float* invl = (float*)(ws + 49545216);    // 737,280 B
  float* wbuf = (float*)(ws + 50282496);    // 1,280 B
  u16* rpartT = (u16*)(ws + 50283776);      // 94,371,840 B (bf16)
  // W^T hi/lo temporaries aliased into rpartT region (consumed before attn writes)
  u16* wqh = (u16*)(ws + 50283776);
  u16* wql = wqh + 106496;
  u16* wkh = wql + 106496;
  u16* wkl = wkh + 106496;
  u16* wvh = wkl + 106496;
  u16* wvl = wvh + 98304;

  convert_w<<<1216, 256, 0, stream>>>(Wq, Wk, Wv, wqh, wql, wkh, wkl, wvh, wvl);
  proj_mfma<416, 0><<<36, 256, 0, stream>>>(Q, wqh, wql, qhi);
  proj_mfma<416, 1><<<720, 256, 0, stream>>>(dbk, wkh, wkl, kvswz);
  proj_mfma<384, 2><<<720, 256, 0, stream>>>(dbv, wvh, wvl, kvswz);
  attn_kernel<<<2880, 512, 0, stream>>>(qhi, kvswz, rpartT, invl);
  weight_kernel<<<dim3(8, 4), 256, 0, stream>>>(invl, p, wbuf);
  reduce_out_k<<<2304, 256, 0, stream>>>(rpartT, wbuf, out);
}

// Round 17
// 284.341 us; speedup vs baseline: 1.2308x; 1.2308x over previous
//
#include <hip/hip_runtime.h>

typedef float f32x4 __attribute__((ext_vector_type(4)));
typedef short bf16x8 __attribute__((ext_vector_type(8)));
typedef unsigned short u16;
typedef unsigned int u32;

#define SCALE 0.0625f
#define MFMA32(a, b, c) __builtin_amdgcn_mfma_f32_16x16x32_bf16((a), (b), (c), 0, 0, 0)

__device__ inline u16 f2bf(float x) {
  u32 u = __float_as_uint(x);
  u32 r = u + 0x7FFFu + ((u >> 16) & 1u);
  return (u16)(r >> 16);
}
__device__ inline float bf2f(u16 h) { return __uint_as_float(((u32)h) << 16); }
// packed f32x2 -> bf16x2 (RNE), single VALU op
__device__ __forceinline__ u32 cvtpk(float a, float b) {
  u32 r;
  asm("v_cvt_pk_bf16_f32 %0, %1, %2" : "=v"(r) : "v"(a), "v"(b));
  return r;
}

// async global->LDS, 16B per lane; LDS dest is wave-uniform base + lane*16
__device__ __forceinline__ void gld16(const void* g, void* l) {
  __builtin_amdgcn_global_load_lds(
      (const __attribute__((address_space(1))) unsigned int*)(uintptr_t)g,
      (__attribute__((address_space(3))) unsigned int*)(uintptr_t)l, 16, 0, 0);
}

// ---------------------------------------------------------------------------
// Transpose+split W matrices: W[k][n] fp32 -> Wt_hi/lo[n][k] bf16.
// ---------------------------------------------------------------------------
__global__ __launch_bounds__(256) void convert_w(
    const float* __restrict__ Wq, const float* __restrict__ Wk, const float* __restrict__ Wv,
    u16* __restrict__ qh, u16* __restrict__ qlo2, u16* __restrict__ kh, u16* __restrict__ klo2,
    u16* __restrict__ vh, u16* __restrict__ vlo2) {
  int idx = blockIdx.x * 256 + threadIdx.x;
  const float* src;
  u16 *dh, *dl;
  int KD;
  const int nq = 416 * 256;
  if (idx < nq) {
    src = Wq; dh = qh; dl = qlo2; KD = 416;
  } else if (idx < 2 * nq) {
    idx -= nq; src = Wk; dh = kh; dl = klo2; KD = 416;
  } else {
    idx -= 2 * nq;
    if (idx >= 384 * 256) return;
    src = Wv; dh = vh; dl = vlo2; KD = 384;
  }
  int k = idx >> 8, n = idx & 255;
  float x = src[idx];
  u16 h = f2bf(x);
  dh[n * KD + k] = h;
  dl[n * KD + k] = f2bf(x - bf2f(h));
}

// ---------------------------------------------------------------------------
// Fused Q+K projection (KD=416), 2-term split-bf16 MFMA: C = ah*(Wh+Wl).
// Blocks 0..719: K path (A=dbk, W=wk) -> kvswz swizzled image (OUT1).
// Blocks 720..755: Q path (A=Q, W=wq) -> flat hi [m][256] (OUT0).
// Inner loop identical to the r13/r15-proven proj_mfma.
// ---------------------------------------------------------------------------
__global__ __launch_bounds__(256, 3) void proj_fused416(
    const float* __restrict__ Aq, const float* __restrict__ Ak,
    const u16* __restrict__ wqh, const u16* __restrict__ wql,
    const u16* __restrict__ wkh, const u16* __restrict__ wkl,
    u16* __restrict__ qout, u16* __restrict__ kvswz) {
  __shared__ u16 Ah[64 * 32];
  __shared__ u16 Wh[256 * 32], Wl[256 * 32];
  const int t = threadIdx.x;
  const int w = t >> 6, l = t & 63;
  const int lr = l & 15, lk = l >> 4;
  const bool kmode = blockIdx.x < 720;
  const int m0 = (kmode ? blockIdx.x : (blockIdx.x - 720)) * 64;
  const float* A = kmode ? Ak : Aq;
  const u16* wth = kmode ? wkh : wqh;
  const u16* wtl = kmode ? wkl : wql;
  const int KD = 416;
  f32x4 acc[16];
#pragma unroll
  for (int i = 0; i < 16; ++i) acc[i] = {};
  const int arow = t >> 2, ac = t & 3;
  const int acp = (ac + (arow >> 1)) & 3;
  for (int k0 = 0; k0 < KD; k0 += 32) {
    __syncthreads();
    {
      const float* s1 = A + (size_t)(m0 + arow) * KD + k0 + ac * 8;
      float4 f1 = *(const float4*)s1;
      float4 f2 = *(const float4*)(s1 + 4);
      u32 hv[4];
      hv[0] = cvtpk(f1.x, f1.y);
      hv[1] = cvtpk(f1.z, f1.w);
      hv[2] = cvtpk(f2.x, f2.y);
      hv[3] = cvtpk(f2.z, f2.w);
      *(bf16x8*)(Ah + arow * 32 + acp * 8) = *(bf16x8*)hv;
#pragma unroll
      for (int i = 0; i < 4; ++i) {
        int ch = t + i * 256;
        int n = ch >> 2, c = ch & 3;
        int cp = (c + (n >> 1)) & 3;
        *(bf16x8*)(Wh + n * 32 + cp * 8) = *(const bf16x8*)(wth + (size_t)n * KD + k0 + c * 8);
        *(bf16x8*)(Wl + n * 32 + cp * 8) = *(const bf16x8*)(wtl + (size_t)n * KD + k0 + c * 8);
      }
    }
    __syncthreads();
    const int row = w * 16 + lr;
    const int rcp = (lk + (row >> 1)) & 3;
    bf16x8 ah = *(const bf16x8*)(Ah + row * 32 + rcp * 8);
#pragma unroll
    for (int fc = 0; fc < 16; ++fc) {
      int n = lr + 16 * fc;
      int cp = (lk + (n >> 1)) & 3;
      bf16x8 bh = *(const bf16x8*)(Wh + n * 32 + cp * 8);
      bf16x8 bl = *(const bf16x8*)(Wl + n * 32 + cp * 8);
      acc[fc] = MFMA32(ah, bh, acc[fc]);
      acc[fc] = MFMA32(ah, bl, acc[fc]);
    }
  }
  if (kmode) {
#pragma unroll
    for (int r = 0; r < 4; ++r) {
      int m = m0 + w * 16 + lk * 4 + r;
      int km = m / 576;
      int j = m - km * 576;
      int kt = j >> 6, row = j & 63;
      size_t rowbase = (size_t)(km * 9 + kt) * 32768 + (row << 8);
#pragma unroll
      for (int fc = 0; fc < 16; ++fc) {
        int c = (lr >> 3) + 2 * fc;
        size_t slot = rowbase + (size_t)((((c + 5 * row) & 31) << 3) + (lr & 7));
        kvswz[slot] = f2bf(acc[fc][r]);
      }
    }
  } else {
#pragma unroll
    for (int fc = 0; fc < 16; ++fc) {
      int n = lr + 16 * fc;
#pragma unroll
      for (int r = 0; r < 4; ++r) {
        int m = m0 + w * 16 + lk * 4 + r;
        qout[(size_t)m * 256 + n] = f2bf(acc[fc][r]);
      }
    }
  }
}

// ---------------------------------------------------------------------------
// V projection (KD=384), 2-term split-bf16 MFMA -> kvswz V region (r13-proven)
// ---------------------------------------------------------------------------
__global__ __launch_bounds__(256, 3) void proj_v384(
    const float* __restrict__ A, const u16* __restrict__ wth, const u16* __restrict__ wtl,
    u16* __restrict__ oh) {
  __shared__ u16 Ah[64 * 32];
  __shared__ u16 Wh[256 * 32], Wl[256 * 32];
  const int t = threadIdx.x;
  const int w = t >> 6, l = t & 63;
  const int lr = l & 15, lk = l >> 4;
  const int m0 = blockIdx.x * 64;
  const int KD = 384;
  f32x4 acc[16];
#pragma unroll
  for (int i = 0; i < 16; ++i) acc[i] = {};
  const int arow = t >> 2, ac = t & 3;
  const int acp = (ac + (arow >> 1)) & 3;
  for (int k0 = 0; k0 < KD; k0 += 32) {
    __syncthreads();
    {
      const float* s1 = A + (size_t)(m0 + arow) * KD + k0 + ac * 8;
      float4 f1 = *(const float4*)s1;
      float4 f2 = *(const float4*)(s1 + 4);
      u32 hv[4];
      hv[0] = cvtpk(f1.x, f1.y);
      hv[1] = cvtpk(f1.z, f1.w);
      hv[2] = cvtpk(f2.x, f2.y);
      hv[3] = cvtpk(f2.z, f2.w);
      *(bf16x8*)(Ah + arow * 32 + acp * 8) = *(bf16x8*)hv;
#pragma unroll
      for (int i = 0; i < 4; ++i) {
        int ch = t + i * 256;
        int n = ch >> 2, c = ch & 3;
        int cp = (c + (n >> 1)) & 3;
        *(bf16x8*)(Wh + n * 32 + cp * 8) = *(const bf16x8*)(wth + (size_t)n * KD + k0 + c * 8);
        *(bf16x8*)(Wl + n * 32 + cp * 8) = *(const bf16x8*)(wtl + (size_t)n * KD + k0 + c * 8);
      }
    }
    __syncthreads();
    const int row = w * 16 + lr;
    const int rcp = (lk + (row >> 1)) & 3;
    bf16x8 ah = *(const bf16x8*)(Ah + row * 32 + rcp * 8);
#pragma unroll
    for (int fc = 0; fc < 16; ++fc) {
      int n = lr + 16 * fc;
      int cp = (lk + (n >> 1)) & 3;
      bf16x8 bh = *(const bf16x8*)(Wh + n * 32 + cp * 8);
      bf16x8 bl = *(const bf16x8*)(Wl + n * 32 + cp * 8);
      acc[fc] = MFMA32(ah, bh, acc[fc]);
      acc[fc] = MFMA32(ah, bl, acc[fc]);
    }
  }
  {
    const int km = m0 / 576;
    const int j0 = (m0 % 576) + w * 16 + lk * 4;
    const int kt = j0 >> 6;
    const int jl = j0 & 63;
    const int kc = jl >> 3, e0 = jl & 7;
    const size_t vbase = (size_t)(km * 9 + kt) * 32768 + 16384;
#pragma unroll
    for (int fc = 0; fc < 16; ++fc) {
      size_t slot = vbase + (size_t)((fc >> 1) * 2048 + ((kc * 32 + lr + (fc & 1) * 16) << 3) + e0);
      u32 pk[2];
      pk[0] = cvtpk(acc[fc][0], acc[fc][1]);
      pk[1] = cvtpk(acc[fc][2], acc[fc][3]);
      *(uint2*)(oh + slot) = *(uint2*)pk;
    }
  }
}

// ---------------------------------------------------------------------------
// Flash attention (r15-proven, 183 us): 512 thr / 8 waves = (wq 0..3) x
// (wk 0..1); 64 q x 64 keys/kt (9 iterations).  S = qh*kh; PV = ph*vh.
// K staged block-wide (4 DMAs/thread), V staged wave-self-sliced (4 DMAs/
// thread into its own 4 KB).  2 barriers/kt, counted vmcnt only.
// m==0 softmax, stats reduced once at end.  R written [b,km][d][n] as BF16.
// ---------------------------------------------------------------------------
__global__ __launch_bounds__(512, 4) void attn_kernel(
    const u16* __restrict__ qhi, const u16* __restrict__ kvswz,
    u16* __restrict__ rpartT, float* __restrict__ invl) {
  __shared__ u16 KV[32768];  // u16: [Kh 16384 = 64 rows x 256][Vh 16384]
  __shared__ u16 Ph[64 * 72];
  __shared__ float lred[2][64], mred[2][64];
  __shared__ float invs[64];
  const int t = threadIdx.x;
  const int w = t >> 6, l = t & 63;
  const int lr = l & 15, lk = l >> 4;
  const int wq = w >> 1, wk = w & 1;
  // XCD-cluster swizzle: all 36 blocks of one km land on xcd = km%8.
  const int L = blockIdx.x;
  const int xcd = L & 7, slot = L >> 3;
  const int km = xcd + 8 * (slot / 36);
  const int inner = slot % 36;
  const int b = inner & 3, qb = inner >> 2;
  const int qw = qb * 64 + wq * 16;

  // Q fragments (B-operand of swapped QK: col=q=lr, k-chunk lk*8 + s*32)
  bf16x8 qh[8];
  {
    const size_t qoff = ((size_t)(b * 576 + qw + lr)) * 256 + lk * 8;
#pragma unroll
    for (int s = 0; s < 8; ++s) qh[s] = *(const bf16x8*)(qhi + qoff + s * 32);
  }

  f32x4 o[4][2];
#pragma unroll
  for (int i = 0; i < 4; ++i)
#pragma unroll
    for (int j = 0; j < 2; ++j) o[i][j] = {};
  float m_part = -1e30f, l_part = 0.f;  // per-lane: q=wq*16+lr, keys of wk half

  const char* kvb = (const char*)kvswz + (size_t)(km * 9) * 65536;
  char* lds0 = (char*)&KV[0];

  auto STAGE_K = [&](int kt) {
    const char* src = kvb + (size_t)kt * 65536 + t * 16;
    char* dst = lds0 + t * 16;
#pragma unroll
    for (int i = 0; i < 4; ++i) gld16(src + i * 8192, dst + i * 8192);
  };
  auto STAGE_V = [&](int kt) {
    // wave-self slice: bytes 32768 + w*4096 .. +4096
    const char* src = kvb + (size_t)kt * 65536 + 32768 + w * 4096 + l * 16;
    char* dst = lds0 + 32768 + w * 4096 + l * 16;
#pragma unroll
    for (int c = 0; c < 4; ++c) gld16(src + c * 1024, dst + c * 1024);
  };

  // prologue
  asm volatile("s_waitcnt vmcnt(0)" ::: "memory");  // Q drained: clean FIFO
  __builtin_amdgcn_sched_barrier(0);
  STAGE_K(0);
  __builtin_amdgcn_sched_barrier(0);
  STAGE_V(0);
  asm volatile("s_waitcnt vmcnt(4)" ::: "memory");  // K(0) landed, V(0) in flight
  __builtin_amdgcn_sched_barrier(0);
  __builtin_amdgcn_s_barrier();
  __builtin_amdgcn_sched_barrier(0);

  const int krow0 = wk * 32 + lr;
  const int krow1 = wk * 32 + 16 + lr;

  for (int kt = 0; kt < 9; ++kt) {
    // ---- QK^T: A = K-frags (two 16-key blocks of wk half), B = Q
    f32x4 s0 = {}, s1 = {};
    __builtin_amdgcn_s_setprio(1);
#pragma unroll
    for (int s = 0; s < 8; ++s) {
      const int cc0 = ((s * 4 + lk) + 5 * krow0) & 31;
      const int cc1 = ((s * 4 + lk) + 5 * krow1) & 31;
      bf16x8 k0 = *(const bf16x8*)(KV + krow0 * 256 + cc0 * 8);
      bf16x8 k1 = *(const bf16x8*)(KV + krow1 * 256 + cc1 * 8);
      s0 = MFMA32(k0, qh[s], s0);
      s1 = MFMA32(k1, qh[s], s1);
    }
    __builtin_amdgcn_s_setprio(0);

    // ---- P = exp(S*scale): lane q = wq*16+lr; keys wk*32 + {lk*4.., 16+lk*4..}
    float e0[4], e1[4];
#pragma unroll
    for (int r = 0; r < 4; ++r) {
      float a0 = s0[r] * SCALE;
      float a1 = s1[r] * SCALE;
      m_part = fmaxf(m_part, fmaxf(a0, a1));
      e0[r] = __expf(a0);
      e1[r] = __expf(a1);
      l_part += e0[r] + e1[r];
    }
    {
      u32 pk0[2], pk1[2];
      pk0[0] = cvtpk(e0[0], e0[1]);
      pk0[1] = cvtpk(e0[2], e0[3]);
      pk1[0] = cvtpk(e1[0], e1[1]);
      pk1[1] = cvtpk(e1[2], e1[3]);
      int pb = (wq * 16 + lr) * 72 + wk * 32 + lk * 4;
      *(uint2*)(Ph + pb) = *(uint2*)pk0;
      *(uint2*)(Ph + pb + 16) = *(uint2*)pk1;
    }
    asm volatile("s_waitcnt lgkmcnt(0)" ::: "memory");  // K reads + P writes done
    __builtin_amdgcn_sched_barrier(0);
    __builtin_amdgcn_s_barrier();  // B1: P visible, K region free
    __builtin_amdgcn_sched_barrier(0);

    const int ktn = kt < 8 ? kt + 1 : 8;
    STAGE_K(ktn);  // flies under PV
    __builtin_amdgcn_sched_barrier(0);
    asm volatile("s_waitcnt vmcnt(4)" ::: "memory");  // my V(kt) landed
    __builtin_amdgcn_sched_barrier(0);

    // ---- PV: wave covers d = w*32 + dt*16 + lr, keys in two 32-halves (ks)
    __builtin_amdgcn_s_setprio(1);
#pragma unroll
    for (int ks = 0; ks < 2; ++ks) {
      bf16x8 vhf[2];
#pragma unroll
      for (int dt = 0; dt < 2; ++dt)
        vhf[dt] = *(const bf16x8*)(KV + 16384 + w * 2048 + ((ks * 4 + lk) * 32 + dt * 16 + lr) * 8);
#pragma unroll
      for (int qt = 0; qt < 4; ++qt) {
        bf16x8 pah = *(const bf16x8*)(Ph + (qt * 16 + lr) * 72 + ks * 32 + lk * 8);
#pragma unroll
        for (int dt = 0; dt < 2; ++dt)
          o[qt][dt] = MFMA32(pah, vhf[dt], o[qt][dt]);
      }
    }
    __builtin_amdgcn_s_setprio(0);
    asm volatile("s_waitcnt lgkmcnt(0)" ::: "memory");  // V/P reads done
    __builtin_amdgcn_sched_barrier(0);
    STAGE_V(ktn);  // safe: only this wave reads its V slice
    __builtin_amdgcn_sched_barrier(0);
    asm volatile("s_waitcnt vmcnt(4)" ::: "memory");  // my K(kt+1) landed
    __builtin_amdgcn_sched_barrier(0);
    __builtin_amdgcn_s_barrier();  // B2: all K landed, P region free
    __builtin_amdgcn_sched_barrier(0);
  }

  // ---- stats: lane q=wq*16+lr; combine lk groups then wk halves
  {
    float lv = l_part, mv = m_part;
    lv += __shfl_xor(lv, 16, 64);
    mv = fmaxf(mv, __shfl_xor(mv, 16, 64));
    lv += __shfl_xor(lv, 32, 64);
    mv = fmaxf(mv, __shfl_xor(mv, 32, 64));
    if (l < 16) {
      lred[wk][wq * 16 + l] = lv;
      mred[wk][wq * 16 + l] = mv;
    }
  }
  __syncthreads();
  if (w == 0) {
    float ls = lred[0][l] + lred[1][l];
    float mv = fmaxf(mred[0][l], mred[1][l]);
    invs[l] = 1.0f / ls;
    invl[(size_t)(b * 80 + km) * 576 + qb * 64 + l] = __expf(mv) / ls;
  }
  __syncthreads();

  u16* dst = rpartT + (size_t)(b * 80 + km) * 147456;
#pragma unroll
  for (int qt = 0; qt < 4; ++qt) {
    float iv[4];
#pragma unroll
    for (int r = 0; r < 4; ++r) iv[r] = invs[qt * 16 + lk * 4 + r];
#pragma unroll
    for (int dt = 0; dt < 2; ++dt) {
      int d = w * 32 + dt * 16 + lr;
      u32 pk[2];
      pk[0] = cvtpk(o[qt][dt][0] * iv[0], o[qt][dt][1] * iv[1]);
      pk[1] = cvtpk(o[qt][dt][2] * iv[2], o[qt][dt][3] * iv[3]);
      *(uint2*)(dst + (size_t)d * 576 + qb * 64 + qt * 16 + lk * 4) = *(uint2*)pk;
    }
  }
}

// ---------------------------------------------------------------------------
// Weights: s[b,k,m] = mean_n 1/l_ref ; w = gate(p) * s / (sum_m s + 1e-8)
// ---------------------------------------------------------------------------
__global__ __launch_bounds__(256) void weight_kernel(const float* __restrict__ invl,
                                                     const float* __restrict__ p,
                                                     float* __restrict__ wout) {
  const int k = blockIdx.x, b = blockIdx.y;
  __shared__ float sm[10];
  __shared__ float red[4];
  const int t = threadIdx.x;
  for (int m = 0; m < 10; ++m) {
    float part = 0.f;
    for (int n = t; n < 576; n += 256)
      part += invl[(size_t)((b * 8 + k) * 10 + m) * 576 + n];
#pragma unroll
    for (int off = 32; off; off >>= 1) part += __shfl_down(part, off, 64);
    if ((t & 63) == 0) red[t >> 6] = part;
    __syncthreads();
    if (t == 0) sm[m] = (red[0] + red[1] + red[2] + red[3]) * (1.0f / 576.0f);
    __syncthreads();
  }
  if (t == 0) {
    float tot = 0.f;
    for (int m = 0; m < 10; ++m) tot += sm[m];
    float pmax = fmaxf(fmaxf(p[0 * 8 + k], p[1 * 8 + k]), fmaxf(p[2 * 8 + k], p[3 * 8 + k]));
    float gate = (pmax >= 0.01f) ? p[b * 8 + k] : 0.0f;
    for (int m = 0; m < 10; ++m)
      wout[(b * 8 + k) * 10 + m] = gate * sm[m] / (tot + 1e-8f);
  }
}

// ---------------------------------------------------------------------------
// out[b][d][n] = sum_km w[b,km] * bf2f(rpartT[b,km][d][n])
// ---------------------------------------------------------------------------
__global__ __launch_bounds__(256) void reduce_out_k(const u16* __restrict__ rpartT,
                                                    const float* __restrict__ wbuf,
                                                    float* __restrict__ out) {
  int idx = blockIdx.x * 256 + threadIdx.x;
  int b = idx / 147456;
  size_t off = (size_t)(idx % 147456);
  const u16* base = rpartT + (size_t)b * 80 * 147456 + off;
  const float* wp = wbuf + b * 80;
  float acc = 0.f;
#pragma unroll 8
  for (int g = 0; g < 80; ++g)
    acc += wp[g] * __uint_as_float(((u32)base[(size_t)g * 147456]) << 16);
  out[idx] = acc;
}

// ---------------------------------------------------------------------------
extern "C" void kernel_launch(void* const* d_in, const int* in_sizes, int n_in,
                              void* d_out, int out_size, void* d_ws, size_t ws_size,
                              hipStream_t stream) {
  const float* Q = (const float*)d_in[0];
  const float* dbk = (const float*)d_in[1];
  const float* dbv = (const float*)d_in[2];
  const float* p = (const float*)d_in[3];
  const float* Wq = (const float*)d_in[4];
  const float* Wk = (const float*)d_in[5];
  const float* Wv = (const float*)d_in[6];
  float* out = (float*)d_out;
  char* ws = (char*)d_ws;

  u16* qhi = (u16*)(ws);                    // 1,179,648 B
  u16* kvswz = (u16*)(ws + 2359296);        // 80*9*65536 = 47,185,920 B
  float* invl = (float*)(ws + 49545216);    // 737,280 B
  float* wbuf = (float*)(ws + 50282496);    // 1,280 B
  u16* rpartT = (u16*)(ws + 50283776);      // 94,371,840 B (bf16)
  // W^T hi/lo temporaries aliased into rpartT region (consumed before attn writes)
  u16* wqh = (u16*)(ws + 50283776);
  u16* wql = wqh + 106496;
  u16* wkh = wql + 106496;
  u16* wkl = wkh + 106496;
  u16* wvh = wkl + 106496;
  u16* wvl = wvh + 98304;

  convert_w<<<1216, 256, 0, stream>>>(Wq, Wk, Wv, wqh, wql, wkh, wkl, wvh, wvl);
  proj_fused416<<<756, 256, 0, stream>>>(Q, dbk, wqh, wql, wkh, wkl, qhi, kvswz);
  proj_v384<<<720, 256, 0, stream>>>(dbv, wvh, wvl, kvswz);
  attn_kernel<<<2880, 512, 0, stream>>>(qhi, kvswz, rpartT, invl);
  weight_kernel<<<dim3(8, 4), 256, 0, stream>>>(invl, p, wbuf);
  reduce_out_k<<<2304, 256, 0, stream>>>(rpartT, wbuf, out);
}

// Round 18
// 275.856 us; speedup vs baseline: 1.2687x; 1.0308x over previous
//
#include <hip/hip_runtime.h>

typedef float f32x4 __attribute__((ext_vector_type(4)));
typedef short bf16x8 __attribute__((ext_vector_type(8)));
typedef unsigned short u16;
typedef unsigned int u32;

#define SCALE 0.0625f
#define MFMA32(a, b, c) __builtin_amdgcn_mfma_f32_16x16x32_bf16((a), (b), (c), 0, 0, 0)

__device__ inline u16 f2bf(float x) {
  u32 u = __float_as_uint(x);
  u32 r = u + 0x7FFFu + ((u >> 16) & 1u);
  return (u16)(r >> 16);
}
__device__ inline float bf2f(u16 h) { return __uint_as_float(((u32)h) << 16); }
// packed f32x2 -> bf16x2 (RNE), single VALU op
__device__ __forceinline__ u32 cvtpk(float a, float b) {
  u32 r;
  asm("v_cvt_pk_bf16_f32 %0, %1, %2" : "=v"(r) : "v"(a), "v"(b));
  return r;
}

// async global->LDS, 16B per lane; LDS dest is wave-uniform base + lane*16
__device__ __forceinline__ void gld16(const void* g, void* l) {
  __builtin_amdgcn_global_load_lds(
      (const __attribute__((address_space(1))) unsigned int*)(uintptr_t)g,
      (__attribute__((address_space(3))) unsigned int*)(uintptr_t)l, 16, 0, 0);
}

// ---------------------------------------------------------------------------
// Transpose+split W matrices: W[k][n] fp32 -> Wt_hi/lo[n][k] bf16.
// ---------------------------------------------------------------------------
__global__ __launch_bounds__(256) void convert_w(
    const float* __restrict__ Wq, const float* __restrict__ Wk, const float* __restrict__ Wv,
    u16* __restrict__ qh, u16* __restrict__ qlo2, u16* __restrict__ kh, u16* __restrict__ klo2,
    u16* __restrict__ vh, u16* __restrict__ vlo2) {
  int idx = blockIdx.x * 256 + threadIdx.x;
  const float* src;
  u16 *dh, *dl;
  int KD;
  const int nq = 416 * 256;
  if (idx < nq) {
    src = Wq; dh = qh; dl = qlo2; KD = 416;
  } else if (idx < 2 * nq) {
    idx -= nq; src = Wk; dh = kh; dl = klo2; KD = 416;
  } else {
    idx -= 2 * nq;
    if (idx >= 384 * 256) return;
    src = Wv; dh = vh; dl = vlo2; KD = 384;
  }
  int k = idx >> 8, n = idx & 255;
  float x = src[idx];
  u16 h = f2bf(x);
  dh[n * KD + k] = h;
  dl[n * KD + k] = f2bf(x - bf2f(h));
}

// ---------------------------------------------------------------------------
// Unified projection GEMM, 2-term split-bf16 MFMA: C = ah*(Wh+Wl), with
// register-prefetch pipeline (k0+1 global loads fly under k0's MFMA phase).
// Blocks [0,720):   K mode -> kvswz K image    (KD=416)
// Blocks [720,1440):V mode -> kvswz V image    (KD=384)
// Blocks [1440,1476): Q mode -> flat hi [m][256] (KD=416)
// Epilogues byte-identical to the r13/r17-proven versions.
// ---------------------------------------------------------------------------
__global__ __launch_bounds__(256, 3) void proj_all(
    const float* __restrict__ Qin, const float* __restrict__ dbk, const float* __restrict__ dbv,
    const u16* __restrict__ wqh, const u16* __restrict__ wql,
    const u16* __restrict__ wkh, const u16* __restrict__ wkl,
    const u16* __restrict__ wvh, const u16* __restrict__ wvl,
    u16* __restrict__ qout, u16* __restrict__ kvswz) {
  __shared__ u16 Ah[64 * 32];
  __shared__ u16 Wh[256 * 32], Wl[256 * 32];
  const int t = threadIdx.x;
  const int w = t >> 6, l = t & 63;
  const int lr = l & 15, lk = l >> 4;
  const int bx = blockIdx.x;
  const int mode = bx < 720 ? 1 : (bx < 1440 ? 2 : 0);  // 1=K, 2=V, 0=Q
  const int m0 = (mode == 1 ? bx : (mode == 2 ? bx - 720 : bx - 1440)) * 64;
  const float* A = mode == 1 ? dbk : (mode == 2 ? dbv : Qin);
  const u16* wth = mode == 1 ? wkh : (mode == 2 ? wvh : wqh);
  const u16* wtl = mode == 1 ? wkl : (mode == 2 ? wvl : wql);
  const int KD = (mode == 2) ? 384 : 416;
  const int nk = KD >> 5;

  f32x4 acc[16];
#pragma unroll
  for (int i = 0; i < 16; ++i) acc[i] = {};
  const int arow = t >> 2, ac = t & 3;
  const int acp = (ac + (arow >> 1)) & 3;
  // W staging geometry (4 chunks/thread)
  int wn[4], wc[4], wcp[4];
#pragma unroll
  for (int i = 0; i < 4; ++i) {
    int ch = t + i * 256;
    wn[i] = ch >> 2;
    wc[i] = ch & 3;
    wcp[i] = (wc[i] + (wn[i] >> 1)) & 3;
  }

  // prefetch registers
  float4 pa0, pa1;
  bf16x8 pwh[4], pwl[4];
  {
    const float* s1 = A + (size_t)(m0 + arow) * KD + ac * 8;
    pa0 = *(const float4*)s1;
    pa1 = *(const float4*)(s1 + 4);
#pragma unroll
    for (int i = 0; i < 4; ++i) {
      pwh[i] = *(const bf16x8*)(wth + (size_t)wn[i] * KD + wc[i] * 8);
      pwl[i] = *(const bf16x8*)(wtl + (size_t)wn[i] * KD + wc[i] * 8);
    }
  }

  for (int it = 0; it < nk; ++it) {
    // stash prefetched regs into LDS (implicit vmcnt waits here)
    {
      u32 hv[4];
      hv[0] = cvtpk(pa0.x, pa0.y);
      hv[1] = cvtpk(pa0.z, pa0.w);
      hv[2] = cvtpk(pa1.x, pa1.y);
      hv[3] = cvtpk(pa1.z, pa1.w);
      *(bf16x8*)(Ah + arow * 32 + acp * 8) = *(bf16x8*)hv;
#pragma unroll
      for (int i = 0; i < 4; ++i) {
        *(bf16x8*)(Wh + wn[i] * 32 + wcp[i] * 8) = pwh[i];
        *(bf16x8*)(Wl + wn[i] * 32 + wcp[i] * 8) = pwl[i];
      }
    }
    __syncthreads();  // LDS ready for MFMA
    if (it + 1 < nk) {
      const int k0 = (it + 1) * 32;
      const float* s1 = A + (size_t)(m0 + arow) * KD + k0 + ac * 8;
      pa0 = *(const float4*)s1;
      pa1 = *(const float4*)(s1 + 4);
#pragma unroll
      for (int i = 0; i < 4; ++i) {
        pwh[i] = *(const bf16x8*)(wth + (size_t)wn[i] * KD + k0 + wc[i] * 8);
        pwl[i] = *(const bf16x8*)(wtl + (size_t)wn[i] * KD + k0 + wc[i] * 8);
      }
    }
    const int row = w * 16 + lr;
    const int rcp = (lk + (row >> 1)) & 3;
    bf16x8 ah = *(const bf16x8*)(Ah + row * 32 + rcp * 8);
#pragma unroll
    for (int fc = 0; fc < 16; ++fc) {
      int n = lr + 16 * fc;
      int cp = (lk + (n >> 1)) & 3;
      bf16x8 bh = *(const bf16x8*)(Wh + n * 32 + cp * 8);
      bf16x8 bl = *(const bf16x8*)(Wl + n * 32 + cp * 8);
      acc[fc] = MFMA32(ah, bh, acc[fc]);
      acc[fc] = MFMA32(ah, bl, acc[fc]);
    }
    __syncthreads();  // all LDS reads done; safe to overwrite next iter
  }

  if (mode == 1) {
#pragma unroll
    for (int r = 0; r < 4; ++r) {
      int m = m0 + w * 16 + lk * 4 + r;
      int km = m / 576;
      int j = m - km * 576;
      int kt = j >> 6, row = j & 63;
      size_t rowbase = (size_t)(km * 9 + kt) * 32768 + (row << 8);
#pragma unroll
      for (int fc = 0; fc < 16; ++fc) {
        int c = (lr >> 3) + 2 * fc;
        size_t slot = rowbase + (size_t)((((c + 5 * row) & 31) << 3) + (lr & 7));
        kvswz[slot] = f2bf(acc[fc][r]);
      }
    }
  } else if (mode == 2) {
    const int km = m0 / 576;
    const int j0 = (m0 % 576) + w * 16 + lk * 4;
    const int kt = j0 >> 6;
    const int jl = j0 & 63;
    const int kc = jl >> 3, e0 = jl & 7;
    const size_t vbase = (size_t)(km * 9 + kt) * 32768 + 16384;
#pragma unroll
    for (int fc = 0; fc < 16; ++fc) {
      size_t slot = vbase + (size_t)((fc >> 1) * 2048 + ((kc * 32 + lr + (fc & 1) * 16) << 3) + e0);
      u32 pk[2];
      pk[0] = cvtpk(acc[fc][0], acc[fc][1]);
      pk[1] = cvtpk(acc[fc][2], acc[fc][3]);
      *(uint2*)(kvswz + slot) = *(uint2*)pk;
    }
  } else {
#pragma unroll
    for (int fc = 0; fc < 16; ++fc) {
      int n = lr + 16 * fc;
#pragma unroll
      for (int r = 0; r < 4; ++r) {
        int m = m0 + w * 16 + lk * 4 + r;
        qout[(size_t)m * 256 + n] = f2bf(acc[fc][r]);
      }
    }
  }
}

// ---------------------------------------------------------------------------
// Flash attention (r15-proven, 183 us): 512 thr / 8 waves = (wq 0..3) x
// (wk 0..1); 64 q x 64 keys/kt (9 iterations).  S = qh*kh; PV = ph*vh.
// K staged block-wide (4 DMAs/thread), V staged wave-self-sliced (4 DMAs/
// thread into its own 4 KB).  2 barriers/kt, counted vmcnt only.
// m==0 softmax, stats reduced once at end.  R written [b,km][d][n] as BF16.
// ---------------------------------------------------------------------------
__global__ __launch_bounds__(512, 4) void attn_kernel(
    const u16* __restrict__ qhi, const u16* __restrict__ kvswz,
    u16* __restrict__ rpartT, float* __restrict__ invl) {
  __shared__ u16 KV[32768];  // u16: [Kh 16384 = 64 rows x 256][Vh 16384]
  __shared__ u16 Ph[64 * 72];
  __shared__ float lred[2][64], mred[2][64];
  __shared__ float invs[64];
  const int t = threadIdx.x;
  const int w = t >> 6, l = t & 63;
  const int lr = l & 15, lk = l >> 4;
  const int wq = w >> 1, wk = w & 1;
  // XCD-cluster swizzle: all 36 blocks of one km land on xcd = km%8.
  const int L = blockIdx.x;
  const int xcd = L & 7, slot = L >> 3;
  const int km = xcd + 8 * (slot / 36);
  const int inner = slot % 36;
  const int b = inner & 3, qb = inner >> 2;
  const int qw = qb * 64 + wq * 16;

  // Q fragments (B-operand of swapped QK: col=q=lr, k-chunk lk*8 + s*32)
  bf16x8 qh[8];
  {
    const size_t qoff = ((size_t)(b * 576 + qw + lr)) * 256 + lk * 8;
#pragma unroll
    for (int s = 0; s < 8; ++s) qh[s] = *(const bf16x8*)(qhi + qoff + s * 32);
  }

  f32x4 o[4][2];
#pragma unroll
  for (int i = 0; i < 4; ++i)
#pragma unroll
    for (int j = 0; j < 2; ++j) o[i][j] = {};
  float m_part = -1e30f, l_part = 0.f;  // per-lane: q=wq*16+lr, keys of wk half

  const char* kvb = (const char*)kvswz + (size_t)(km * 9) * 65536;
  char* lds0 = (char*)&KV[0];

  auto STAGE_K = [&](int kt) {
    const char* src = kvb + (size_t)kt * 65536 + t * 16;
    char* dst = lds0 + t * 16;
#pragma unroll
    for (int i = 0; i < 4; ++i) gld16(src + i * 8192, dst + i * 8192);
  };
  auto STAGE_V = [&](int kt) {
    // wave-self slice: bytes 32768 + w*4096 .. +4096
    const char* src = kvb + (size_t)kt * 65536 + 32768 + w * 4096 + l * 16;
    char* dst = lds0 + 32768 + w * 4096 + l * 16;
#pragma unroll
    for (int c = 0; c < 4; ++c) gld16(src + c * 1024, dst + c * 1024);
  };

  // prologue
  asm volatile("s_waitcnt vmcnt(0)" ::: "memory");  // Q drained: clean FIFO
  __builtin_amdgcn_sched_barrier(0);
  STAGE_K(0);
  __builtin_amdgcn_sched_barrier(0);
  STAGE_V(0);
  asm volatile("s_waitcnt vmcnt(4)" ::: "memory");  // K(0) landed, V(0) in flight
  __builtin_amdgcn_sched_barrier(0);
  __builtin_amdgcn_s_barrier();
  __builtin_amdgcn_sched_barrier(0);

  const int krow0 = wk * 32 + lr;
  const int krow1 = wk * 32 + 16 + lr;

  for (int kt = 0; kt < 9; ++kt) {
    // ---- QK^T: A = K-frags (two 16-key blocks of wk half), B = Q
    f32x4 s0 = {}, s1 = {};
    __builtin_amdgcn_s_setprio(1);
#pragma unroll
    for (int s = 0; s < 8; ++s) {
      const int cc0 = ((s * 4 + lk) + 5 * krow0) & 31;
      const int cc1 = ((s * 4 + lk) + 5 * krow1) & 31;
      bf16x8 k0 = *(const bf16x8*)(KV + krow0 * 256 + cc0 * 8);
      bf16x8 k1 = *(const bf16x8*)(KV + krow1 * 256 + cc1 * 8);
      s0 = MFMA32(k0, qh[s], s0);
      s1 = MFMA32(k1, qh[s], s1);
    }
    __builtin_amdgcn_s_setprio(0);

    // ---- P = exp(S*scale): lane q = wq*16+lr; keys wk*32 + {lk*4.., 16+lk*4..}
    float e0[4], e1[4];
#pragma unroll
    for (int r = 0; r < 4; ++r) {
      float a0 = s0[r] * SCALE;
      float a1 = s1[r] * SCALE;
      m_part = fmaxf(m_part, fmaxf(a0, a1));
      e0[r] = __expf(a0);
      e1[r] = __expf(a1);
      l_part += e0[r] + e1[r];
    }
    {
      u32 pk0[2], pk1[2];
      pk0[0] = cvtpk(e0[0], e0[1]);
      pk0[1] = cvtpk(e0[2], e0[3]);
      pk1[0] = cvtpk(e1[0], e1[1]);
      pk1[1] = cvtpk(e1[2], e1[3]);
      int pb = (wq * 16 + lr) * 72 + wk * 32 + lk * 4;
      *(uint2*)(Ph + pb) = *(uint2*)pk0;
      *(uint2*)(Ph + pb + 16) = *(uint2*)pk1;
    }
    asm volatile("s_waitcnt lgkmcnt(0)" ::: "memory");  // K reads + P writes done
    __builtin_amdgcn_sched_barrier(0);
    __builtin_amdgcn_s_barrier();  // B1: P visible, K region free
    __builtin_amdgcn_sched_barrier(0);

    const int ktn = kt < 8 ? kt + 1 : 8;
    STAGE_K(ktn);  // flies under PV
    __builtin_amdgcn_sched_barrier(0);
    asm volatile("s_waitcnt vmcnt(4)" ::: "memory");  // my V(kt) landed
    __builtin_amdgcn_sched_barrier(0);

    // ---- PV: wave covers d = w*32 + dt*16 + lr, keys in two 32-halves (ks)
    __builtin_amdgcn_s_setprio(1);
#pragma unroll
    for (int ks = 0; ks < 2; ++ks) {
      bf16x8 vhf[2];
#pragma unroll
      for (int dt = 0; dt < 2; ++dt)
        vhf[dt] = *(const bf16x8*)(KV + 16384 + w * 2048 + ((ks * 4 + lk) * 32 + dt * 16 + lr) * 8);
#pragma unroll
      for (int qt = 0; qt < 4; ++qt) {
        bf16x8 pah = *(const bf16x8*)(Ph + (qt * 16 + lr) * 72 + ks * 32 + lk * 8);
#pragma unroll
        for (int dt = 0; dt < 2; ++dt)
          o[qt][dt] = MFMA32(pah, vhf[dt], o[qt][dt]);
      }
    }
    __builtin_amdgcn_s_setprio(0);
    asm volatile("s_waitcnt lgkmcnt(0)" ::: "memory");  // V/P reads done
    __builtin_amdgcn_sched_barrier(0);
    STAGE_V(ktn);  // safe: only this wave reads its V slice
    __builtin_amdgcn_sched_barrier(0);
    asm volatile("s_waitcnt vmcnt(4)" ::: "memory");  // my K(kt+1) landed
    __builtin_amdgcn_sched_barrier(0);
    __builtin_amdgcn_s_barrier();  // B2: all K landed, P region free
    __builtin_amdgcn_sched_barrier(0);
  }

  // ---- stats: lane q=wq*16+lr; combine lk groups then wk halves
  {
    float lv = l_part, mv = m_part;
    lv += __shfl_xor(lv, 16, 64);
    mv = fmaxf(mv, __shfl_xor(mv, 16, 64));
    lv += __shfl_xor(lv, 32, 64);
    mv = fmaxf(mv, __shfl_xor(mv, 32, 64));
    if (l < 16) {
      lred[wk][wq * 16 + l] = lv;
      mred[wk][wq * 16 + l] = mv;
    }
  }
  __syncthreads();
  if (w == 0) {
    float ls = lred[0][l] + lred[1][l];
    float mv = fmaxf(mred[0][l], mred[1][l]);
    invs[l] = 1.0f / ls;
    invl[(size_t)(b * 80 + km) * 576 + qb * 64 + l] = __expf(mv) / ls;
  }
  __syncthreads();

  u16* dst = rpartT + (size_t)(b * 80 + km) * 147456;
#pragma unroll
  for (int qt = 0; qt < 4; ++qt) {
    float iv[4];
#pragma unroll
    for (int r = 0; r < 4; ++r) iv[r] = invs[qt * 16 + lk * 4 + r];
#pragma unroll
    for (int dt = 0; dt < 2; ++dt) {
      int d = w * 32 + dt * 16 + lr;
      u32 pk[2];
      pk[0] = cvtpk(o[qt][dt][0] * iv[0], o[qt][dt][1] * iv[1]);
      pk[1] = cvtpk(o[qt][dt][2] * iv[2], o[qt][dt][3] * iv[3]);
      *(uint2*)(dst + (size_t)d * 576 + qb * 64 + qt * 16 + lk * 4) = *(uint2*)pk;
    }
  }
}

// ---------------------------------------------------------------------------
// Weights: s[b,k,m] = mean_n 1/l_ref ; w = gate(p) * s / (sum_m s + 1e-8)
// ---------------------------------------------------------------------------
__global__ __launch_bounds__(256) void weight_kernel(const float* __restrict__ invl,
                                                     const float* __restrict__ p,
                                                     float* __restrict__ wout) {
  const int k = blockIdx.x, b = blockIdx.y;
  __shared__ float sm[10];
  __shared__ float red[4];
  const int t = threadIdx.x;
  for (int m = 0; m < 10; ++m) {
    float part = 0.f;
    for (int n = t; n < 576; n += 256)
      part += invl[(size_t)((b * 8 + k) * 10 + m) * 576 + n];
#pragma unroll
    for (int off = 32; off; off >>= 1) part += __shfl_down(part, off, 64);
    if ((t & 63) == 0) red[t >> 6] = part;
    __syncthreads();
    if (t == 0) sm[m] = (red[0] + red[1] + red[2] + red[3]) * (1.0f / 576.0f);
    __syncthreads();
  }
  if (t == 0) {
    float tot = 0.f;
    for (int m = 0; m < 10; ++m) tot += sm[m];
    float pmax = fmaxf(fmaxf(p[0 * 8 + k], p[1 * 8 + k]), fmaxf(p[2 * 8 + k], p[3 * 8 + k]));
    float gate = (pmax >= 0.01f) ? p[b * 8 + k] : 0.0f;
    for (int m = 0; m < 10; ++m)
      wout[(b * 8 + k) * 10 + m] = gate * sm[m] / (tot + 1e-8f);
  }
}

// ---------------------------------------------------------------------------
// out[b][d][n] = sum_km w[b,km] * bf2f(rpartT[b,km][d][n])
// ---------------------------------------------------------------------------
__global__ __launch_bounds__(256) void reduce_out_k(const u16* __restrict__ rpartT,
                                                    const float* __restrict__ wbuf,
                                                    float* __restrict__ out) {
  int idx = blockIdx.x * 256 + threadIdx.x;
  int b = idx / 147456;
  size_t off = (size_t)(idx % 147456);
  const u16* base = rpartT + (size_t)b * 80 * 147456 + off;
  const float* wp = wbuf + b * 80;
  float acc = 0.f;
#pragma unroll 8
  for (int g = 0; g < 80; ++g)
    acc += wp[g] * __uint_as_float(((u32)base[(size_t)g * 147456]) << 16);
  out[idx] = acc;
}

// ---------------------------------------------------------------------------
extern "C" void kernel_launch(void* const* d_in, const int* in_sizes, int n_in,
                              void* d_out, int out_size, void* d_ws, size_t ws_size,
                              hipStream_t stream) {
  const float* Q = (const float*)d_in[0];
  const float* dbk = (const float*)d_in[1];
  const float* dbv = (const float*)d_in[2];
  const float* p = (const float*)d_in[3];
  const float* Wq = (const float*)d_in[4];
  const float* Wk = (const float*)d_in[5];
  const float* Wv = (const float*)d_in[6];
  float* out = (float*)d_out;
  char* ws = (char*)d_ws;

  u16* qhi = (u16*)(ws);                    // 1,179,648 B
  u16* kvswz = (u16*)(ws + 2359296);        // 80*9*65536 = 47,185,920 B
  float* invl = (float*)(ws + 49545216);    // 737,280 B
  float* wbuf = (float*)(ws + 50282496);    // 1,280 B
  u16* rpartT = (u16*)(ws + 50283776);      // 94,371,840 B (bf16)
  // W^T hi/lo temporaries aliased into rpartT region (consumed before attn writes)
  u16* wqh = (u16*)(ws + 50283776);
  u16* wql = wqh + 106496;
  u16* wkh = wql + 106496;
  u16* wkl = wkh + 106496;
  u16* wvh = wkl + 106496;
  u16* wvl = wvh + 98304;

  convert_w<<<1216, 256, 0, stream>>>(Wq, Wk, Wv, wqh, wql, wkh, wkl, wvh, wvl);
  proj_all<<<1476, 256, 0, stream>>>(Q, dbk, dbv, wqh, wql, wkh, wkl, wvh, wvl, qhi, kvswz);
  attn_kernel<<<2880, 512, 0, stream>>>(qhi, kvswz, rpartT, invl);
  weight_kernel<<<dim3(8, 4), 256, 0, stream>>>(invl, p, wbuf);
  reduce_out_k<<<2304, 256, 0, stream>>>(rpartT, wbuf, out);
}